// Round 9
// baseline (3682.242 us; speedup 1.0000x reference)
//
#include <hip/hip_runtime.h>
#include <hip/hip_bf16.h>
#include <hip/hip_cooperative_groups.h>

namespace cg = cooperative_groups;

// Problem constants (fixed by setup_inputs)
#define BATCH 512
#define HDIM  1024
#define G4    4096   // 4*H
#define DSTEP 64
#define NOUT  512
#define HB    ((size_t)BATCH * HDIM)

typedef __bf16 bf16;
typedef __bf16 bf16x8 __attribute__((ext_vector_type(8)));
typedef float  f32x4  __attribute__((ext_vector_type(4)));

#define MFMA16(a, b, c) __builtin_amdgcn_mfma_f32_16x16x32_bf16((a), (b), (c), 0, 0, 0)

#define GLOAD_LDS16(g, l)                                                           \
    __builtin_amdgcn_global_load_lds((const __attribute__((address_space(1))) void*)(g), \
                                     (__attribute__((address_space(3))) void*)(l), 16, 0, 0)

__device__ __forceinline__ float sigmoid_f(float x) { return 1.0f / (1.0f + __expf(-x)); }
__device__ __forceinline__ float tanh_f(float x)    { return 1.0f - 2.0f / (__expf(2.0f * x) + 1.0f); }

// segment swizzle for [row][32] bf16 LDS tiles (4 segments of 16B per 64B row)
__device__ __forceinline__ int swz4(int row) { return (row ^ (row >> 2)) & 3; }

// ---------------- prep: fp32 -> bf16 conversions + layout transforms ----------------
// Whh is written GATE-INTERLEAVED: row' = hcol*4 + gate
__global__ void prep_kernel(const float* __restrict__ x, const float* __restrict__ h0,
                            const float* __restrict__ W_ih, const float* __restrict__ W_hh,
                            const float* __restrict__ W_out,
                            bf16* __restrict__ x_b, bf16* __restrict__ Wih_b,
                            bf16* __restrict__ Whh_i, bf16* __restrict__ Wout_b,
                            bf16* __restrict__ h_slot0) {
    int tid = blockIdx.x * blockDim.x + threadIdx.x;
    int stride = gridDim.x * blockDim.x;
    for (int i = tid; i < G4 * HDIM; i += stride) {
        int r = i >> 10, k = i & 1023;
        int r2 = ((r & 1023) << 2) | (r >> 10);   // interleave: hcol*4 + gate
        Whh_i[(size_t)r2 * HDIM + k] = (bf16)W_hh[i];
        Wih_b[i] = (bf16)W_ih[i];
    }
    for (int i = tid; i < BATCH * HDIM; i += stride) {
        x_b[i]     = (bf16)x[i];
        Wout_b[i]  = (bf16)W_out[i];
        h_slot0[i] = (bf16)h0[i];
    }
}

// ---------------- tiled C = A @ B^T + bias(+bias2) (bf16 in, f32 out) ----------------
// 128x128 tile, BK=32, double-buffered LDS via global_load_lds(16B), 4 waves (64x64 each).
// INTER: store columns gate-interleaved (col' = (col&1023)*4 + col>>10).
template <int M, int N, int K, bool INTER>
__global__ __launch_bounds__(256) void gemm_bt_tiled(const bf16* __restrict__ A,
                                                     const bf16* __restrict__ Bw,
                                                     const float* __restrict__ bias,
                                                     const float* __restrict__ bias2,
                                                     float* __restrict__ C) {
    constexpr int MT = M / 128;
    constexpr int NT = N / 128;
    constexpr int TOT = MT * NT;
    __shared__ bf16 sA[2][128 * 32];
    __shared__ bf16 sB[2][128 * 32];

    int bid = blockIdx.x;
    int g = (bid & 7) * (TOT / 8) + (bid >> 3);  // XCD-chunked
    int nt = g % NT, mt = g / NT;
    int mrow0 = mt * 128, ncol0 = nt * 128;

    int tid = threadIdx.x;
    int l = tid & 63;
    int w = tid >> 6;
    int wr = w >> 1, wc = w & 1;
    int lr = l & 15, q = l >> 4;

    const bf16* Abase = A + (size_t)mrow0 * K;
    const bf16* Bbase = Bw + (size_t)ncol0 * K;

    auto stage = [&](const bf16* base, bf16* dst, int k0) {
#pragma unroll
        for (int j = 0; j < 2; ++j) {
            int pbase = w * 64 + 256 * j;
            int p = pbase + l;
            int row = p >> 2, seg = p & 3;
            int sseg = seg ^ swz4(row);
            const bf16* gp = base + (size_t)row * K + k0 + sseg * 8;
            GLOAD_LDS16(gp, dst + pbase * 8);
        }
    };

    stage(Abase, sA[0], 0);
    stage(Bbase, sB[0], 0);
    __syncthreads();

    f32x4 acc[4][4] = {};
    constexpr int NS = K / 32;
    for (int s = 0; s < NS; ++s) {
        int cur = s & 1;
        if (s + 1 < NS) {
            stage(Abase, sA[cur ^ 1], (s + 1) * 32);
            stage(Bbase, sB[cur ^ 1], (s + 1) * 32);
        }
        bf16x8 af[4], bf[4];
#pragma unroll
        for (int fm = 0; fm < 4; ++fm) {
            int row = wr * 64 + fm * 16 + lr;
            af[fm] = *(const bf16x8*)&sA[cur][row * 32 + 8 * (q ^ swz4(row))];
        }
#pragma unroll
        for (int fn = 0; fn < 4; ++fn) {
            int row = wc * 64 + fn * 16 + lr;
            bf[fn] = *(const bf16x8*)&sB[cur][row * 32 + 8 * (q ^ swz4(row))];
        }
#pragma unroll
        for (int fm = 0; fm < 4; ++fm)
#pragma unroll
            for (int fn = 0; fn < 4; ++fn)
                acc[fm][fn] = MFMA16(af[fm], bf[fn], acc[fm][fn]);
        __syncthreads();
    }

#pragma unroll
    for (int fm = 0; fm < 4; ++fm)
#pragma unroll
        for (int fn = 0; fn < 4; ++fn) {
            int col = ncol0 + wc * 64 + fn * 16 + lr;
            float bs = bias[col] + (bias2 ? bias2[col] : 0.0f);
            int colw = INTER ? (((col & 1023) << 2) | (col >> 10)) : col;
#pragma unroll
            for (int r = 0; r < 4; ++r) {
                int row = mrow0 + wr * 64 + fm * 16 + q * 4 + r;
                C[(size_t)row * N + colw] = acc[fm][fn][r] + bs;
            }
        }
}

// ---------------- persistent LSTM scan v2 (cooperative, spill-proofed) ----------------
// 256 blocks x 512 threads, 1 block/CU (2 waves/SIMD -> 256 VGPR budget, pinned).
// Block tile: 64 batch rows x 128 gatecols (32 hcols). 8 waves = cw(4 col-quarters) x kw(2 K-halves).
// Whh panel in REGISTERS for the whole scan (Breg: 128 VGPR). c in registers (never in memory).
// xW re-read from L2 each step (read-only -> stays valid inside one kernel).
// Per step: stage h panel to LDS (128 KB, swizzle pair) -> K-loop (ds_read A x Breg MFMA)
// -> kw-reduce via LDS -> gate combine -> elementwise -> h write -> grid.sync.
__global__ __launch_bounds__(512) __attribute__((amdgpu_waves_per_eu(2, 2)))
void persistent_lstm2(const bf16* __restrict__ Whh_i,   // [4096][1024], gate-interleaved rows
                      const float* __restrict__ xWi,    // [512][4096], gate-interleaved cols, biases folded
                      const float* __restrict__ c0,     // [512][1024] f32
                      bf16* __restrict__ h_all)         // [65][512][1024] bf16
{
    __shared__ __align__(16) char smem[131072];      // 128 KB
    bf16*  A_lds = (bf16*)smem;                      // [64 rows][128 segs of 16B]
    float* red   = (float*)smem;                     // 32 KB alias (dead-A region)
    float* gbuf  = (float*)(smem + 32768);           // 32 KB alias

    int bid = blockIdx.x;
    int nb = bid & 31;        // gatecol panel 0..31
    int mb = bid >> 5;        // batch panel 0..7

    int tid = threadIdx.x;
    int l   = tid & 63;
    int wid = tid >> 6;       // 0..7
    int cw  = wid & 3;        // col quarter (32 gatecols)
    int kw  = wid >> 2;       // K half (512)
    int lr = l & 15, q = l >> 4;

    int row0 = mb * 64;
    int gc0  = nb * 128 + cw * 32;

    // ---- B stash: 32 gatecols x 512 K in regs (16 kc x 2 fn x bf16x8 = 128 VGPR) ----
    bf16x8 Breg[16][2];
#pragma unroll
    for (int kc = 0; kc < 16; ++kc)
#pragma unroll
        for (int fn = 0; fn < 2; ++fn)
            Breg[kc][fn] = *(const bf16x8*)&Whh_i[(size_t)(gc0 + fn * 16 + lr) * HDIM +
                                                  kw * 512 + kc * 32 + q * 8];

    // ---- c stash: 4 (row,hcol) elems/thread, block-private for the whole scan ----
    float cst[4];
#pragma unroll
    for (int it = 0; it < 4; ++it) {
        int idx = it * 512 + tid;
        int row = idx >> 5, hl = idx & 31;
        cst[it] = c0[(size_t)(row0 + row) * HDIM + nb * 32 + hl];
    }

    cg::grid_group grid = cg::this_grid();

    for (int t = 0; t < DSTEP; ++t) {
        // ---- stage h[t] panel (64x1024, 128 KB): linear dest + pre-swizzled source ----
        const bf16* hsrc = h_all + (size_t)t * HB + (size_t)row0 * HDIM;
#pragma unroll
        for (int jj = 0; jj < 16; ++jj) {
            int base = jj * 512 + wid * 64;          // wave-uniform 16B-slot base
            int p = base + l;
            int rown = p >> 7, ss = p & 127;
            int sg = ss ^ (rown & 7);
            GLOAD_LDS16(hsrc + (size_t)rown * HDIM + sg * 8, A_lds + (size_t)base * 8);
        }
        __syncthreads();

        // ---- K-loop: 16 chunks of K=32; A from LDS, B from registers ----
        f32x4 acc[4][2] = {};
#pragma unroll
        for (int kc = 0; kc < 16; ++kc) {
            bf16x8 af[4];
#pragma unroll
            for (int fm = 0; fm < 4; ++fm) {
                int rown = fm * 16 + lr;
                int s = kw * 64 + kc * 4 + q;
                af[fm] = *(const bf16x8*)&A_lds[(size_t)(rown * 128 + (s ^ (rown & 7))) * 8];
            }
#pragma unroll
            for (int fm = 0; fm < 4; ++fm) {
                acc[fm][0] = MFMA16(af[fm], Breg[kc][0], acc[fm][0]);
                acc[fm][1] = MFMA16(af[fm], Breg[kc][1], acc[fm][1]);
            }
        }
        __syncthreads();   // A_lds dead -> safe to alias red/gbuf

        // ---- kw reduce (register-exact slot map) ----
        if (kw == 1) {
#pragma unroll
            for (int fm = 0; fm < 4; ++fm)
#pragma unroll
                for (int fn = 0; fn < 2; ++fn)
#pragma unroll
                    for (int r = 0; r < 4; ++r)
                        red[(((cw * 4 + fm) * 2 + fn) * 4 + r) * 64 + l] = acc[fm][fn][r];
        }
        __syncthreads();
        if (kw == 0) {
#pragma unroll
            for (int fm = 0; fm < 4; ++fm)
#pragma unroll
                for (int fn = 0; fn < 2; ++fn) {
                    int col = cw * 32 + fn * 16 + lr;
#pragma unroll
                    for (int r = 0; r < 4; ++r) {
                        float v = acc[fm][fn][r] +
                                  red[(((cw * 4 + fm) * 2 + fn) * 4 + r) * 64 + l];
                        int row = fm * 16 + q * 4 + r;
                        gbuf[row * 128 + (col ^ ((row & 7) << 2))] = v;
                    }
                }
        }
        __syncthreads();

        // ---- fused LSTM elementwise: 64 rows x 32 hcols (gates adjacent, float4) ----
        bf16* hdst = h_all + (size_t)(t + 1) * HB;
#pragma unroll
        for (int it = 0; it < 4; ++it) {
            int idx = it * 512 + tid;
            int row = idx >> 5, hl = idx & 31;
            int grow = row0 + row;
            int hcol = nb * 32 + hl;
            float4 g4 = *(const float4*)&gbuf[row * 128 + ((hl * 4) ^ ((row & 7) << 2))];
            float4 xw = *(const float4*)&xWi[(size_t)grow * G4 + (size_t)hcol * 4];
            float gi = g4.x + xw.x;
            float gf = g4.y + xw.y;
            float gg = g4.z + xw.z;
            float go = g4.w + xw.w;
            float cn = sigmoid_f(gf) * cst[it] + sigmoid_f(gi) * tanh_f(gg);
            float hn = sigmoid_f(go) * tanh_f(cn);
            cst[it] = cn;
            hdst[(size_t)grow * HDIM + hcol] = (bf16)hn;
        }
        if (t + 1 < DSTEP) grid.sync();   // release h[t+1] to all XCDs
    }
}

// ---------------- launch ----------------
extern "C" void kernel_launch(void* const* d_in, const int* in_sizes, int n_in,
                              void* d_out, int out_size, void* d_ws, size_t ws_size,
                              hipStream_t stream) {
    const float* x    = (const float*)d_in[0];
    const float* h0   = (const float*)d_in[1];
    const float* c0   = (const float*)d_in[2];
    const float* W_ih = (const float*)d_in[3];
    const float* W_hh = (const float*)d_in[4];
    const float* b_ih = (const float*)d_in[5];
    const float* b_hh = (const float*)d_in[6];
    const float* W_out= (const float*)d_in[7];
    const float* b_out= (const float*)d_in[8];

    char* ws = (char*)d_ws;
    bf16*  Whh_i  = (bf16*)(ws + 0);                     // 8 MB (gate-interleaved)
    bf16*  Wih_b  = (bf16*)(ws + (size_t)(8 << 20));     // 8 MB
    bf16*  x_b    = (bf16*)(ws + (size_t)(16 << 20));    // 1 MB
    bf16*  Wout_b = (bf16*)(ws + (size_t)(17 << 20));    // 1 MB
    float* xWbuf  = (float*)(ws + (size_t)(18 << 20));   // 8 MB (interleaved cols, biases folded)
    bf16*  h_all  = (bf16*)(ws + (size_t)(28 << 20));    // 65 MB (65 slots of 512x1024)

    prep_kernel<<<2048, 256, 0, stream>>>(x, h0, W_ih, W_hh, W_out,
                                          x_b, Wih_b, Whh_i, Wout_b, h_all);

    // xWi = x @ W_ih^T + b_ih + b_hh, stored gate-interleaved: M=512, N=4096 -> 128 blocks
    gemm_bt_tiled<BATCH, G4, HDIM, true><<<128, 256, 0, stream>>>(x_b, Wih_b, b_ih, b_hh, xWbuf);

    // all 64 LSTM steps in ONE cooperative persistent kernel
    {
        const bf16*  whh_arg  = Whh_i;
        const float* xwi_arg  = xWbuf;
        const float* c0_arg   = c0;
        bf16*        hall_arg = h_all;
        void* kargs[] = {(void*)&whh_arg, (void*)&xwi_arg, (void*)&c0_arg, (void*)&hall_arg};
        hipLaunchCooperativeKernel((const void*)persistent_lstm2, dim3(256), dim3(512),
                                   kargs, 0, stream);
    }

    // outs = h_all[1..64] @ W_out^T + b_out : M=32768, N=512 -> 1024 blocks
    gemm_bt_tiled<DSTEP * BATCH, NOUT, HDIM, false><<<1024, 256, 0, stream>>>(
        h_all + HB, Wout_b, b_out, nullptr, (float*)d_out);
}

// Round 11
// 2296.256 us; speedup vs baseline: 1.6036x; 1.6036x over previous
//
#include <hip/hip_runtime.h>
#include <hip/hip_bf16.h>
#include <hip/hip_cooperative_groups.h>

namespace cg = cooperative_groups;

// Problem constants (fixed by setup_inputs)
#define BATCH 512
#define HDIM  1024
#define G4    4096   // 4*H
#define DSTEP 64
#define NOUT  512
#define HB    ((size_t)BATCH * HDIM)

typedef __bf16 bf16;
typedef __bf16 bf16x8 __attribute__((ext_vector_type(8)));
typedef float  f32x4  __attribute__((ext_vector_type(4)));
typedef unsigned long long u64;

#define MFMA16(a, b, c) __builtin_amdgcn_mfma_f32_16x16x32_bf16((a), (b), (c), 0, 0, 0)

#define GLOAD_LDS16(g, l)                                                           \
    __builtin_amdgcn_global_load_lds((const __attribute__((address_space(1))) void*)(g), \
                                     (__attribute__((address_space(3))) void*)(l), 16, 0, 0)

__device__ __forceinline__ float sigmoid_f(float x) { return 1.0f / (1.0f + __expf(-x)); }
__device__ __forceinline__ float tanh_f(float x)    { return 1.0f - 2.0f / (__expf(2.0f * x) + 1.0f); }

__device__ __forceinline__ int swz4(int row) { return (row ^ (row >> 2)) & 3; }

// ---------------- prep: fp32 -> bf16 conversions + layout transforms ----------------
__global__ void prep_kernel(const float* __restrict__ x, const float* __restrict__ h0,
                            const float* __restrict__ W_ih, const float* __restrict__ W_hh,
                            const float* __restrict__ W_out,
                            bf16* __restrict__ x_b, bf16* __restrict__ Wih_b,
                            bf16* __restrict__ Whh_i, bf16* __restrict__ Wout_b,
                            bf16* __restrict__ h_slot0, unsigned int* __restrict__ flags) {
    int tid = blockIdx.x * blockDim.x + threadIdx.x;
    int stride = gridDim.x * blockDim.x;
    if (blockIdx.x == 0 && threadIdx.x < 8) flags[threadIdx.x * 64] = 0;  // group counters
    for (int i = tid; i < G4 * HDIM; i += stride) {
        int r = i >> 10, k = i & 1023;
        int r2 = ((r & 1023) << 2) | (r >> 10);   // gate-interleave: row' = hcol*4 + gate
        Whh_i[(size_t)r2 * HDIM + k] = (bf16)W_hh[i];
        Wih_b[i] = (bf16)W_ih[i];
    }
    for (int i = tid; i < BATCH * HDIM; i += stride) {
        x_b[i]     = (bf16)x[i];
        Wout_b[i]  = (bf16)W_out[i];
        h_slot0[i] = (bf16)h0[i];
    }
}

// ---------------- tiled C = A @ B^T + bias(+bias2) (bf16 in, f32 out) ----------------
template <int M, int N, int K, bool INTER>
__global__ __launch_bounds__(256) void gemm_bt_tiled(const bf16* __restrict__ A,
                                                     const bf16* __restrict__ Bw,
                                                     const float* __restrict__ bias,
                                                     const float* __restrict__ bias2,
                                                     float* __restrict__ C) {
    constexpr int MT = M / 128;
    constexpr int NT = N / 128;
    constexpr int TOT = MT * NT;
    __shared__ bf16 sA[2][128 * 32];
    __shared__ bf16 sB[2][128 * 32];

    int bid = blockIdx.x;
    int g = (bid & 7) * (TOT / 8) + (bid >> 3);  // XCD-chunked
    int nt = g % NT, mt = g / NT;
    int mrow0 = mt * 128, ncol0 = nt * 128;

    int tid = threadIdx.x;
    int l = tid & 63;
    int w = tid >> 6;
    int wr = w >> 1, wc = w & 1;
    int lr = l & 15, q = l >> 4;

    const bf16* Abase = A + (size_t)mrow0 * K;
    const bf16* Bbase = Bw + (size_t)ncol0 * K;

    auto stage = [&](const bf16* base, bf16* dst, int k0) {
#pragma unroll
        for (int j = 0; j < 2; ++j) {
            int pbase = w * 64 + 256 * j;
            int p = pbase + l;
            int row = p >> 2, seg = p & 3;
            int sseg = seg ^ swz4(row);
            const bf16* gp = base + (size_t)row * K + k0 + sseg * 8;
            GLOAD_LDS16(gp, dst + pbase * 8);
        }
    };

    stage(Abase, sA[0], 0);
    stage(Bbase, sB[0], 0);
    __syncthreads();

    f32x4 acc[4][4] = {};
    constexpr int NS = K / 32;
    for (int s = 0; s < NS; ++s) {
        int cur = s & 1;
        if (s + 1 < NS) {
            stage(Abase, sA[cur ^ 1], (s + 1) * 32);
            stage(Bbase, sB[cur ^ 1], (s + 1) * 32);
        }
        bf16x8 af[4], bf[4];
#pragma unroll
        for (int fm = 0; fm < 4; ++fm) {
            int row = wr * 64 + fm * 16 + lr;
            af[fm] = *(const bf16x8*)&sA[cur][row * 32 + 8 * (q ^ swz4(row))];
        }
#pragma unroll
        for (int fn = 0; fn < 4; ++fn) {
            int row = wc * 64 + fn * 16 + lr;
            bf[fn] = *(const bf16x8*)&sB[cur][row * 32 + 8 * (q ^ swz4(row))];
        }
#pragma unroll
        for (int fm = 0; fm < 4; ++fm)
#pragma unroll
            for (int fn = 0; fn < 4; ++fn)
                acc[fm][fn] = MFMA16(af[fm], bf[fn], acc[fm][fn]);
        __syncthreads();
    }

#pragma unroll
    for (int fm = 0; fm < 4; ++fm)
#pragma unroll
        for (int fn = 0; fn < 4; ++fn) {
            int col = ncol0 + wc * 64 + fn * 16 + lr;
            float bs = bias[col] + (bias2 ? bias2[col] : 0.0f);
            int colw = INTER ? (((col & 1023) << 2) | (col >> 10)) : col;
#pragma unroll
            for (int r = 0; r < 4; ++r) {
                int row = mrow0 + wr * 64 + fm * 16 + q * 4 + r;
                C[(size_t)row * N + colw] = acc[fm][fn][r] + bs;
            }
        }
}

// ---------------- persistent LSTM scan v3: XCD-local groups, no grid.sync ----------------
// 256 blocks x 512 threads (cooperative launch for co-residency guarantee only).
// GROUPS: mb = bid&7 (64 batch rows each) — batch rows are INDEPENDENT, so groups never
// exchange data; sync is a per-group monotonic atomic counter (32 blocks/group).
// h exchange via __hip_atomic_load/store(RELAXED, AGENT) -> coherence point (L3): no cache
// fences, so Whh stays in Breg registers and xW stays hot in L2 across all 64 steps.
// Per block: 64 rows x 128 gatecols; 8 waves = kw(4 K-quarters) x cw(2 col-halves).
__global__ __launch_bounds__(512) __attribute__((amdgpu_waves_per_eu(2, 2)))
void persistent_lstm3(const bf16* __restrict__ Whh_i,   // [4096][1024], gate-interleaved rows
                      const float* __restrict__ xWi,    // [512][4096], gate-interleaved cols, biases folded
                      const float* __restrict__ c0,     // [512][1024] f32
                      bf16* __restrict__ h_all,         // [65][512][1024] bf16
                      unsigned int* __restrict__ flags) // 8 group counters, 256-B apart
{
    __shared__ __align__(16) char smem[131072];      // 128 KB
    bf16*  A_lds = (bf16*)smem;                      // [64 rows][128 granules of 16B], swizzled
    float* red   = (float*)smem;                     // 96 KB alias (dead-A region)
    float* gbuf  = (float*)(smem + 98304);           // 32 KB alias

    int bid = blockIdx.x;
    int mb = bid & 7;         // batch group == XCD under round-robin (perf only)
    int nb = bid >> 3;        // gatecol panel 0..31
    unsigned int* arrive = flags + mb * 64;

    int tid = threadIdx.x;
    int l   = tid & 63;
    int wid = tid >> 6;       // 0..7
    int kw  = wid >> 1;       // 0..3  K-quarter (256 wide)
    int cw  = wid & 1;        // 0..1  col-half (64 gatecols)
    int lr = l & 15, q = l >> 4;

    int row0 = mb * 64;
    int gc0  = nb * 128 + cw * 64;

    // ---- B stash: 64 gatecols x 256 K in regs (8 kc x 4 fn x bf16x8 = 128 VGPR) ----
    bf16x8 Breg[8][4];
#pragma unroll
    for (int kc = 0; kc < 8; ++kc)
#pragma unroll
        for (int fn = 0; fn < 4; ++fn)
            Breg[kc][fn] = *(const bf16x8*)&Whh_i[(size_t)(gc0 + fn * 16 + lr) * HDIM +
                                                  kw * 256 + kc * 32 + q * 8];

    // ---- epilogue mapping: ONE row + 4 adjacent hcols per thread ----
    int erow = tid >> 3, ecq = tid & 7;
    int hcol0 = nb * 32 + ecq * 4;
    int grow = row0 + erow;

    // xW (+biases) stash (16 VGPR) and c stash (4 VGPR) — constant / private across scan
    float4 xws[4];
#pragma unroll
    for (int j = 0; j < 4; ++j)
        xws[j] = *(const float4*)&xWi[(size_t)grow * G4 + (size_t)(hcol0 + j) * 4];
    float4 cst = *(const float4*)&c0[(size_t)grow * HDIM + hcol0];
    float cstv[4] = {cst.x, cst.y, cst.z, cst.w};

    // staging mapping: thread covers row srow, 16-B granules [sgrp*16, sgrp*16+16)
    int srow = tid & 63, sgrp = tid >> 6;

    for (int t = 0; t < DSTEP; ++t) {
        // ---- stage h[t] panel (64x1024, 128 KB) via coherent (L3) loads ----
        const u64* gsrc = (const u64*)(h_all + (size_t)t * HB + (size_t)(row0 + srow) * HDIM +
                                       sgrp * 128);
        u64 lov[16], hiv[16];
#pragma unroll
        for (int k = 0; k < 16; ++k) {
            lov[k] = __hip_atomic_load(gsrc + 2 * k,     __ATOMIC_RELAXED, __HIP_MEMORY_SCOPE_AGENT);
            hiv[k] = __hip_atomic_load(gsrc + 2 * k + 1, __ATOMIC_RELAXED, __HIP_MEMORY_SCOPE_AGENT);
        }
#pragma unroll
        for (int k = 0; k < 16; ++k) {
            int sg = sgrp * 16 + k;
            uint4 v;
            v.x = (unsigned int)lov[k]; v.y = (unsigned int)(lov[k] >> 32);
            v.z = (unsigned int)hiv[k]; v.w = (unsigned int)(hiv[k] >> 32);
            *(uint4*)&A_lds[(size_t)(srow * 128 + (sg ^ (srow & 7))) * 8] = v;
        }
        __syncthreads();

        // ---- K-loop: 8 chunks of K=32; A from LDS (swizzled), B from registers ----
        f32x4 acc[4][4] = {};
#pragma unroll
        for (int kc = 0; kc < 8; ++kc) {
            bf16x8 afr[4];
#pragma unroll
            for (int fm = 0; fm < 4; ++fm) {
                int rown = fm * 16 + lr;
                int s = kw * 32 + kc * 4 + q;
                afr[fm] = *(const bf16x8*)&A_lds[(size_t)(rown * 128 + (s ^ (rown & 7))) * 8];
            }
#pragma unroll
            for (int fm = 0; fm < 4; ++fm)
#pragma unroll
                for (int fn = 0; fn < 4; ++fn)
                    acc[fm][fn] = MFMA16(afr[fm], Breg[kc][fn], acc[fm][fn]);
        }
        __syncthreads();   // A_lds dead -> safe to alias red/gbuf

        // ---- cross-kw reduce (register-exact slot map) ----
        if (kw > 0) {
            float* dst = red + (size_t)((kw - 1) * 2 + cw) * 4096;
#pragma unroll
            for (int fm = 0; fm < 4; ++fm)
#pragma unroll
                for (int fn = 0; fn < 4; ++fn)
#pragma unroll
                    for (int r = 0; r < 4; ++r)
                        dst[((fm * 4 + fn) * 4 + r) * 64 + l] = acc[fm][fn][r];
        }
        __syncthreads();
        if (kw == 0) {
#pragma unroll
            for (int fm = 0; fm < 4; ++fm)
#pragma unroll
                for (int fn = 0; fn < 4; ++fn) {
                    int col = cw * 64 + fn * 16 + lr;
#pragma unroll
                    for (int r = 0; r < 4; ++r) {
                        float v = acc[fm][fn][r];
#pragma unroll
                        for (int j = 0; j < 3; ++j)
                            v += red[(size_t)(j * 2 + cw) * 4096 + ((fm * 4 + fn) * 4 + r) * 64 + l];
                        int rowg = fm * 16 + q * 4 + r;
                        gbuf[rowg * 128 + (col ^ ((rowg & 7) << 2))] = v;
                    }
                }
        }
        __syncthreads();

        // ---- fused LSTM elementwise: 1 row x 4 hcols per thread ----
        u64 pack = 0;
#pragma unroll
        for (int j = 0; j < 4; ++j) {
            float4 g4 = *(const float4*)&gbuf[erow * 128 + ((ecq * 16 + j * 4) ^ ((erow & 7) << 2))];
            float gi = g4.x + xws[j].x;
            float gf = g4.y + xws[j].y;
            float gg = g4.z + xws[j].z;
            float go = g4.w + xws[j].w;
            float cn = sigmoid_f(gf) * cstv[j] + sigmoid_f(gi) * tanh_f(gg);
            float hn = sigmoid_f(go) * tanh_f(cn);
            cstv[j] = cn;
            bf16 hb = (bf16)hn;
            unsigned short hu = *(unsigned short*)&hb;
            pack |= (u64)hu << (16 * j);
        }
        __hip_atomic_store((u64*)(h_all + (size_t)(t + 1) * HB + (size_t)grow * HDIM + hcol0),
                           pack, __ATOMIC_RELAXED, __HIP_MEMORY_SCOPE_AGENT);

        // ---- group-local barrier (32 blocks), monotonic counter ----
        if (t + 1 < DSTEP) {
            __syncthreads();   // drains vmcnt per wave: all h stores complete at L3
            if (tid == 0) {
                __hip_atomic_fetch_add(arrive, 1u, __ATOMIC_RELAXED, __HIP_MEMORY_SCOPE_AGENT);
                unsigned int target = 32u * (unsigned int)(t + 1);
                while (__hip_atomic_load(arrive, __ATOMIC_RELAXED, __HIP_MEMORY_SCOPE_AGENT) < target)
                    __builtin_amdgcn_s_sleep(2);
            }
            __syncthreads();
        }
    }
}

// ---------------- launch ----------------
extern "C" void kernel_launch(void* const* d_in, const int* in_sizes, int n_in,
                              void* d_out, int out_size, void* d_ws, size_t ws_size,
                              hipStream_t stream) {
    const float* x    = (const float*)d_in[0];
    const float* h0   = (const float*)d_in[1];
    const float* c0   = (const float*)d_in[2];
    const float* W_ih = (const float*)d_in[3];
    const float* W_hh = (const float*)d_in[4];
    const float* b_ih = (const float*)d_in[5];
    const float* b_hh = (const float*)d_in[6];
    const float* W_out= (const float*)d_in[7];
    const float* b_out= (const float*)d_in[8];

    char* ws = (char*)d_ws;
    bf16*  Whh_i  = (bf16*)(ws + 0);                     // 8 MB (gate-interleaved)
    bf16*  Wih_b  = (bf16*)(ws + (size_t)(8 << 20));     // 8 MB
    bf16*  x_b    = (bf16*)(ws + (size_t)(16 << 20));    // 1 MB
    bf16*  Wout_b = (bf16*)(ws + (size_t)(17 << 20));    // 1 MB
    float* xWbuf  = (float*)(ws + (size_t)(18 << 20));   // 8 MB (interleaved cols, biases folded)
    unsigned int* flags = (unsigned int*)(ws + (size_t)(26 << 20));  // 8 counters
    bf16*  h_all  = (bf16*)(ws + (size_t)(28 << 20));    // 65 MB (65 slots of 512x1024)

    prep_kernel<<<2048, 256, 0, stream>>>(x, h0, W_ih, W_hh, W_out,
                                          x_b, Wih_b, Whh_i, Wout_b, h_all, flags);

    // xWi = x @ W_ih^T + b_ih + b_hh, gate-interleaved: M=512, N=4096 -> 128 blocks
    gemm_bt_tiled<BATCH, G4, HDIM, true><<<128, 256, 0, stream>>>(x_b, Wih_b, b_ih, b_hh, xWbuf);

    // all 64 LSTM steps in ONE persistent kernel (cooperative = co-residency guarantee)
    {
        const bf16*   whh_arg  = Whh_i;
        const float*  xwi_arg  = xWbuf;
        const float*  c0_arg   = c0;
        bf16*         hall_arg = h_all;
        unsigned int* flg_arg  = flags;
        void* kargs[] = {(void*)&whh_arg, (void*)&xwi_arg, (void*)&c0_arg,
                         (void*)&hall_arg, (void*)&flg_arg};
        hipLaunchCooperativeKernel((const void*)persistent_lstm3, dim3(256), dim3(512),
                                   kargs, 0, stream);
    }

    // outs = h_all[1..64] @ W_out^T + b_out : M=32768, N=512 -> 1024 blocks
    gemm_bt_tiled<DSTEP * BATCH, NOUT, HDIM, false><<<1024, 256, 0, stream>>>(
        h_all + HB, Wout_b, b_out, nullptr, (float*)d_out);
}

// Round 12
// 1890.020 us; speedup vs baseline: 1.9483x; 1.2149x over previous
//
#include <hip/hip_runtime.h>
#include <hip/hip_bf16.h>

// Problem constants (fixed by setup_inputs)
#define BATCH 512
#define HDIM  1024
#define G4    4096   // 4*H
#define DSTEP 64
#define NOUT  512
#define HB    ((size_t)BATCH * HDIM)

typedef __bf16 bf16;
typedef __bf16 bf16x8 __attribute__((ext_vector_type(8)));
typedef float  f32x4  __attribute__((ext_vector_type(4)));
typedef unsigned long long u64;

#define MFMA16(a, b, c) __builtin_amdgcn_mfma_f32_16x16x32_bf16((a), (b), (c), 0, 0, 0)

#define GLOAD_LDS16(g, l)                                                           \
    __builtin_amdgcn_global_load_lds((const __attribute__((address_space(1))) void*)(g), \
                                     (__attribute__((address_space(3))) void*)(l), 16, 0, 0)

__device__ __forceinline__ float sigmoid_f(float x) { return 1.0f / (1.0f + __expf(-x)); }
__device__ __forceinline__ float tanh_f(float x)    { return 1.0f - 2.0f / (__expf(2.0f * x) + 1.0f); }

__device__ __forceinline__ int swz4(int row) { return (row ^ (row >> 2)) & 3; }

// coherent (L2-bypass) 16B load — pipelined, vmcnt-counted
__device__ __forceinline__ uint4 coh_load16(const void* p) {
    uint4 v;
    asm volatile("global_load_dwordx4 %0, %1, off sc0 sc1" : "=v"(v) : "v"(p));
    return v;
}

// ---------------- prep: fp32 -> bf16 conversions + layout transforms ----------------
__global__ void prep_kernel(const float* __restrict__ x, const float* __restrict__ h0,
                            const float* __restrict__ W_ih, const float* __restrict__ W_hh,
                            const float* __restrict__ W_out,
                            bf16* __restrict__ x_b, bf16* __restrict__ Wih_b,
                            bf16* __restrict__ Whh_i, bf16* __restrict__ Wout_b,
                            bf16* __restrict__ h_slot0, unsigned int* __restrict__ flags) {
    int tid = blockIdx.x * blockDim.x + threadIdx.x;
    int stride = gridDim.x * blockDim.x;
    if (blockIdx.x == 0 && threadIdx.x < 256) flags[threadIdx.x] = 0;  // per-block flag slots
    for (int i = tid; i < G4 * HDIM; i += stride) {
        int r = i >> 10, k = i & 1023;
        int r2 = ((r & 1023) << 2) | (r >> 10);   // gate-interleave: row' = hcol*4 + gate
        Whh_i[(size_t)r2 * HDIM + k] = (bf16)W_hh[i];
        Wih_b[i] = (bf16)W_ih[i];
    }
    for (int i = tid; i < BATCH * HDIM; i += stride) {
        x_b[i]     = (bf16)x[i];
        Wout_b[i]  = (bf16)W_out[i];
        h_slot0[i] = (bf16)h0[i];
    }
}

// ---------------- tiled C = A @ B^T + bias(+bias2) (bf16 in, f32 out) ----------------
template <int M, int N, int K, bool INTER>
__global__ __launch_bounds__(256) void gemm_bt_tiled(const bf16* __restrict__ A,
                                                     const bf16* __restrict__ Bw,
                                                     const float* __restrict__ bias,
                                                     const float* __restrict__ bias2,
                                                     float* __restrict__ C) {
    constexpr int MT = M / 128;
    constexpr int NT = N / 128;
    constexpr int TOT = MT * NT;
    __shared__ bf16 sA[2][128 * 32];
    __shared__ bf16 sB[2][128 * 32];

    int bid = blockIdx.x;
    int g = (bid & 7) * (TOT / 8) + (bid >> 3);  // XCD-chunked
    int nt = g % NT, mt = g / NT;
    int mrow0 = mt * 128, ncol0 = nt * 128;

    int tid = threadIdx.x;
    int l = tid & 63;
    int w = tid >> 6;
    int wr = w >> 1, wc = w & 1;
    int lr = l & 15, q = l >> 4;

    const bf16* Abase = A + (size_t)mrow0 * K;
    const bf16* Bbase = Bw + (size_t)ncol0 * K;

    auto stage = [&](const bf16* base, bf16* dst, int k0) {
#pragma unroll
        for (int j = 0; j < 2; ++j) {
            int pbase = w * 64 + 256 * j;
            int p = pbase + l;
            int row = p >> 2, seg = p & 3;
            int sseg = seg ^ swz4(row);
            const bf16* gp = base + (size_t)row * K + k0 + sseg * 8;
            GLOAD_LDS16(gp, dst + pbase * 8);
        }
    };

    stage(Abase, sA[0], 0);
    stage(Bbase, sB[0], 0);
    __syncthreads();

    f32x4 acc[4][4] = {};
    constexpr int NS = K / 32;
    for (int s = 0; s < NS; ++s) {
        int cur = s & 1;
        if (s + 1 < NS) {
            stage(Abase, sA[cur ^ 1], (s + 1) * 32);
            stage(Bbase, sB[cur ^ 1], (s + 1) * 32);
        }
        bf16x8 af[4], bf[4];
#pragma unroll
        for (int fm = 0; fm < 4; ++fm) {
            int row = wr * 64 + fm * 16 + lr;
            af[fm] = *(const bf16x8*)&sA[cur][row * 32 + 8 * (q ^ swz4(row))];
        }
#pragma unroll
        for (int fn = 0; fn < 4; ++fn) {
            int row = wc * 64 + fn * 16 + lr;
            bf[fn] = *(const bf16x8*)&sB[cur][row * 32 + 8 * (q ^ swz4(row))];
        }
#pragma unroll
        for (int fm = 0; fm < 4; ++fm)
#pragma unroll
            for (int fn = 0; fn < 4; ++fn)
                acc[fm][fn] = MFMA16(af[fm], bf[fn], acc[fm][fn]);
        __syncthreads();
    }

#pragma unroll
    for (int fm = 0; fm < 4; ++fm)
#pragma unroll
        for (int fn = 0; fn < 4; ++fn) {
            int col = ncol0 + wc * 64 + fn * 16 + lr;
            float bs = bias[col] + (bias2 ? bias2[col] : 0.0f);
            int colw = INTER ? (((col & 1023) << 2) | (col >> 10)) : col;
#pragma unroll
            for (int r = 0; r < 4; ++r) {
                int row = mrow0 + wr * 64 + fm * 16 + q * 4 + r;
                C[(size_t)row * N + colw] = acc[fm][fn][r] + bs;
            }
        }
}

// ---------------- persistent LSTM scan v4: pipelined coherent staging + flag-slot sync ----
// 256 blocks x 512 threads (cooperative launch for co-residency). Groups of 32 blocks by
// batch rows (mb); groups are fully independent. Per-block flag slot (no RMW contention):
// writer atomic-stores flag=t+1 after a store-draining __syncthreads; wave 0 sweep-polls
// its group's 32 flags. h staged via inline-asm global_load_dwordx4 sc0 sc1 (coherent,
// pipelined) -> swizzled ds_write. Whh in registers (Breg), c in registers, xW in registers.
__global__ __launch_bounds__(512) __attribute__((amdgpu_waves_per_eu(2, 2)))
void persistent_lstm4(const bf16* __restrict__ Whh_i,   // [4096][1024], gate-interleaved rows
                      const float* __restrict__ xWi,    // [512][4096], gate-interleaved cols, biases folded
                      const float* __restrict__ c0,     // [512][1024] f32
                      bf16* __restrict__ h_all,         // [65][512][1024] bf16
                      unsigned int* __restrict__ flags) // [8 groups][32 blocks] u32
{
    __shared__ __align__(16) char smem[131072];      // 128 KB
    bf16*  A_lds = (bf16*)smem;                      // [64 rows][128 granules of 16B], swizzled
    float* red   = (float*)smem;                     // 96 KB alias (dead-A region)
    float* gbuf  = (float*)(smem + 98304);           // 32 KB alias

    int bid = blockIdx.x;
    int mb = bid & 7;         // batch group (64 rows)
    int nb = bid >> 3;        // gatecol panel 0..31

    int tid = threadIdx.x;
    int l   = tid & 63;
    int wid = tid >> 6;       // 0..7
    int kw  = wid >> 1;       // 0..3  K-quarter (256 wide)
    int cw  = wid & 1;        // 0..1  col-half (64 gatecols)
    int lr = l & 15, q = l >> 4;

    int row0 = mb * 64;
    int gc0  = nb * 128 + cw * 64;

    // ---- B stash: 64 gatecols x 256 K in regs (8 kc x 4 fn x bf16x8 = 128 VGPR) ----
    bf16x8 Breg[8][4];
#pragma unroll
    for (int kc = 0; kc < 8; ++kc)
#pragma unroll
        for (int fn = 0; fn < 4; ++fn)
            Breg[kc][fn] = *(const bf16x8*)&Whh_i[(size_t)(gc0 + fn * 16 + lr) * HDIM +
                                                  kw * 256 + kc * 32 + q * 8];

    // ---- epilogue mapping: ONE row + 4 adjacent hcols per thread ----
    int erow = tid >> 3, ecq = tid & 7;
    int hcol0 = nb * 32 + ecq * 4;
    int grow = row0 + erow;

    float4 xws[4];
#pragma unroll
    for (int j = 0; j < 4; ++j)
        xws[j] = *(const float4*)&xWi[(size_t)grow * G4 + (size_t)(hcol0 + j) * 4];
    float4 cst = *(const float4*)&c0[(size_t)grow * HDIM + hcol0];
    float cstv[4] = {cst.x, cst.y, cst.z, cst.w};

    // staging map: thread covers row srow, 16-B granules sgrp*16 .. +16
    int srow = tid & 63, sgrp = tid >> 6;
    unsigned int* grpflags = flags + mb * 32;
    unsigned int* myflag   = grpflags + nb;

    for (int t = 0; t < DSTEP; ++t) {
        // ---- 1. sweep barrier: wave 0 polls all 32 group flags >= t (read-only) ----
        if (wid == 0) {
            unsigned int tgt = (unsigned int)t;
            for (int guard = 0; guard < (1 << 22); ++guard) {
                unsigned int f = tgt;
                if (l < 32)
                    f = __hip_atomic_load(&grpflags[l], __ATOMIC_RELAXED, __HIP_MEMORY_SCOPE_AGENT);
                if (__all(f >= tgt)) break;
                __builtin_amdgcn_s_sleep(1);
            }
        }
        __syncthreads();

        // ---- 2. stage h[t] panel (64x1024): coherent pipelined loads -> swizzled LDS ----
        const bf16* hp = h_all + (size_t)t * HB + (size_t)(row0 + srow) * HDIM + sgrp * 128;
#pragma unroll
        for (int b2 = 0; b2 < 2; ++b2) {
            uint4 va[8];
#pragma unroll
            for (int k = 0; k < 8; ++k)
                va[k] = coh_load16(hp + (b2 * 8 + k) * 8);
            asm volatile("s_waitcnt vmcnt(0)" ::: "memory");
            __builtin_amdgcn_sched_barrier(0);
#pragma unroll
            for (int k = 0; k < 8; ++k) {
                int sg = sgrp * 16 + b2 * 8 + k;
                *(uint4*)&A_lds[(size_t)(srow * 128 + (sg ^ (srow & 7))) * 8] = va[k];
            }
        }
        __syncthreads();

        // ---- 3. K-loop: 8 chunks of K=32; A from LDS (swizzled), B from registers ----
        f32x4 acc[4][4] = {};
#pragma unroll
        for (int kc = 0; kc < 8; ++kc) {
            bf16x8 afr[4];
#pragma unroll
            for (int fm = 0; fm < 4; ++fm) {
                int rown = fm * 16 + lr;
                int s = kw * 32 + kc * 4 + q;
                afr[fm] = *(const bf16x8*)&A_lds[(size_t)(rown * 128 + (s ^ (rown & 7))) * 8];
            }
#pragma unroll
            for (int fm = 0; fm < 4; ++fm)
#pragma unroll
                for (int fn = 0; fn < 4; ++fn)
                    acc[fm][fn] = MFMA16(afr[fm], Breg[kc][fn], acc[fm][fn]);
        }
        __syncthreads();   // A_lds dead -> safe to alias red/gbuf

        // ---- 4. cross-kw reduce (register-exact slot map) ----
        if (kw > 0) {
            float* dst = red + (size_t)((kw - 1) * 2 + cw) * 4096;
#pragma unroll
            for (int fm = 0; fm < 4; ++fm)
#pragma unroll
                for (int fn = 0; fn < 4; ++fn)
#pragma unroll
                    for (int r = 0; r < 4; ++r)
                        dst[((fm * 4 + fn) * 4 + r) * 64 + l] = acc[fm][fn][r];
        }
        __syncthreads();
        if (kw == 0) {
#pragma unroll
            for (int fm = 0; fm < 4; ++fm)
#pragma unroll
                for (int fn = 0; fn < 4; ++fn) {
                    int col = cw * 64 + fn * 16 + lr;
#pragma unroll
                    for (int r = 0; r < 4; ++r) {
                        float v = acc[fm][fn][r];
#pragma unroll
                        for (int j = 0; j < 3; ++j)
                            v += red[(size_t)(j * 2 + cw) * 4096 + ((fm * 4 + fn) * 4 + r) * 64 + l];
                        int rowg = fm * 16 + q * 4 + r;
                        gbuf[rowg * 128 + (col ^ ((rowg & 7) << 2))] = v;
                    }
                }
        }
        __syncthreads();

        // ---- 5. fused LSTM elementwise: 1 row x 4 hcols per thread ----
        u64 pack = 0;
#pragma unroll
        for (int j = 0; j < 4; ++j) {
            float4 g4 = *(const float4*)&gbuf[erow * 128 + ((ecq * 16 + j * 4) ^ ((erow & 7) << 2))];
            float gi = g4.x + xws[j].x;
            float gf = g4.y + xws[j].y;
            float gg = g4.z + xws[j].z;
            float go = g4.w + xws[j].w;
            float cn = sigmoid_f(gf) * cstv[j] + sigmoid_f(gi) * tanh_f(gg);
            float hn = sigmoid_f(go) * tanh_f(cn);
            cstv[j] = cn;
            bf16 hb = (bf16)hn;
            unsigned short hu = *(unsigned short*)&hb;
            pack |= (u64)hu << (16 * j);
        }
        __hip_atomic_store((u64*)(h_all + (size_t)(t + 1) * HB + (size_t)grow * HDIM + hcol0),
                           pack, __ATOMIC_RELAXED, __HIP_MEMORY_SCOPE_AGENT);

        // ---- 6. publish: drain stores (per-wave vmcnt at barrier), then own flag ----
        if (t + 1 < DSTEP) {
            __syncthreads();
            if (tid == 0)
                __hip_atomic_store(myflag, (unsigned int)(t + 1),
                                   __ATOMIC_RELAXED, __HIP_MEMORY_SCOPE_AGENT);
        }
    }
}

// ---------------- launch ----------------
extern "C" void kernel_launch(void* const* d_in, const int* in_sizes, int n_in,
                              void* d_out, int out_size, void* d_ws, size_t ws_size,
                              hipStream_t stream) {
    const float* x    = (const float*)d_in[0];
    const float* h0   = (const float*)d_in[1];
    const float* c0   = (const float*)d_in[2];
    const float* W_ih = (const float*)d_in[3];
    const float* W_hh = (const float*)d_in[4];
    const float* b_ih = (const float*)d_in[5];
    const float* b_hh = (const float*)d_in[6];
    const float* W_out= (const float*)d_in[7];
    const float* b_out= (const float*)d_in[8];

    char* ws = (char*)d_ws;
    bf16*  Whh_i  = (bf16*)(ws + 0);                     // 8 MB (gate-interleaved)
    bf16*  Wih_b  = (bf16*)(ws + (size_t)(8 << 20));     // 8 MB
    bf16*  x_b    = (bf16*)(ws + (size_t)(16 << 20));    // 1 MB
    bf16*  Wout_b = (bf16*)(ws + (size_t)(17 << 20));    // 1 MB
    float* xWbuf  = (float*)(ws + (size_t)(18 << 20));   // 8 MB (interleaved cols, biases folded)
    unsigned int* flags = (unsigned int*)(ws + (size_t)(26 << 20));  // 256 slots
    bf16*  h_all  = (bf16*)(ws + (size_t)(28 << 20));    // 65 MB (65 slots of 512x1024)

    prep_kernel<<<2048, 256, 0, stream>>>(x, h0, W_ih, W_hh, W_out,
                                          x_b, Wih_b, Whh_i, Wout_b, h_all, flags);

    // xWi = x @ W_ih^T + b_ih + b_hh, gate-interleaved: M=512, N=4096 -> 128 blocks
    gemm_bt_tiled<BATCH, G4, HDIM, true><<<128, 256, 0, stream>>>(x_b, Wih_b, b_ih, b_hh, xWbuf);

    // all 64 LSTM steps in ONE persistent kernel (cooperative = co-residency guarantee)
    {
        const bf16*   whh_arg  = Whh_i;
        const float*  xwi_arg  = xWbuf;
        const float*  c0_arg   = c0;
        bf16*         hall_arg = h_all;
        unsigned int* flg_arg  = flags;
        void* kargs[] = {(void*)&whh_arg, (void*)&xwi_arg, (void*)&c0_arg,
                         (void*)&hall_arg, (void*)&flg_arg};
        hipLaunchCooperativeKernel((const void*)persistent_lstm4, dim3(256), dim3(512),
                                   kargs, 0, stream);
    }

    // outs = h_all[1..64] @ W_out^T + b_out : M=32768, N=512 -> 1024 blocks
    gemm_bt_tiled<DSTEP * BATCH, NOUT, HDIM, false><<<1024, 256, 0, stream>>>(
        h_all + HB, Wout_b, b_out, nullptr, (float*)d_out);
}